// Round 1
// baseline (656.320 us; speedup 1.0000x reference)
//
#include <hip/hip_runtime.h>
#include <math.h>

#define NF 6
#define M2 256            // 16*16 pixels
#define TWO_PI_F 6.283185307179586f

// one block per batch element b; 256 threads
__global__ __launch_bounds__(256) void simflux_kernel(
    const float* __restrict__ params,    // (B,5)
    const float* __restrict__ mod,       // (B,6,6)
    const float* __restrict__ roipos,    // (B,2)
    const float* __restrict__ psf_ev,    // (B,256)
    const float* __restrict__ psf_deriv, // (B,256,5)
    float* __restrict__ out_mu,          // (B,6,256)
    float* __restrict__ out_deriv)       // (B,6,256,5)
{
    const unsigned b = blockIdx.x;
    const unsigned t = threadIdx.x;

    __shared__ float ev_s[M2];       // psf_ev tile
    __shared__ float pd_s[M2 * 5];   // raw psf_deriv tile
    __shared__ float A_s[NF][5];     // coeff on ev_s
    __shared__ float Bc_s[NF][5];    // coeff on pd_s (scale folded in)
    __shared__ float S_s[NF];        // I * intensity (for mu)

    // ---- stage tiles (coalesced) ----
    ev_s[t] = psf_ev[b * M2 + t];
    const float* pdb = psf_deriv + (size_t)b * (M2 * 5);
    #pragma unroll
    for (int i = 0; i < 5; ++i) pd_s[i * 256 + t] = pdb[i * 256 + t];

    const float x   = params[b * 5 + 0];
    const float y   = params[b * 5 + 1];
    const float z   = params[b * 5 + 2];
    const float Iph = params[b * 5 + 3];
    const float bg  = params[b * 5 + 4];

    // ---- per-field modulation coefficients (lanes 0..5) ----
    if (t < NF) {
        const unsigned f = t;
        const float rx = roipos[b * 2 + 0];
        const float ry = roipos[b * 2 + 1];
        const float* mf = mod + ((size_t)b * NF + f) * 6;
        const float k0 = mf[0], k1 = mf[1], k2 = mf[2];
        const float depth = mf[3], phase = mf[4], relint = mf[5];

        float dot = (x + rx) * k0 + (y + ry) * k1 + z * k2;
        float r = fmodf(dot, TWO_PI_F);
        if (r < 0.f) r += TWO_PI_F;
        const float em = r - phase;
        const float sn = sinf(em);
        const float cs = cosf(em);

        const float intensity = (1.f + depth * sn) * relint;
        const float dcr = depth * cs * relint;   // * k_c -> mod_deriv_c
        const float sI  = Iph * intensity;

        A_s[f][0] = Iph * dcr * k0;
        A_s[f][1] = Iph * dcr * k1;
        A_s[f][2] = Iph * dcr * k2;
        A_s[f][3] = intensity;
        A_s[f][4] = 0.f;
        Bc_s[f][0] = sI * (1.0f / 65.0f);
        Bc_s[f][1] = sI * (1.0f / 65.0f);
        Bc_s[f][2] = sI * 0.001f;
        Bc_s[f][3] = 0.f;
        Bc_s[f][4] = 0.f;
        S_s[f] = sI;
    }
    __syncthreads();

    // ---- mu: 6*256 = 1536 floats = 768 float2 per block ----
    float2* mu2 = (float2*)(out_mu + (size_t)b * (NF * M2));
    #pragma unroll
    for (int j = 0; j < 3; ++j) {
        const unsigned q = j * 256 + t;      // float2 index in [0,768)
        const unsigned f = q >> 7;           // 128 float2 per field
        const unsigned p = (q & 127u) * 2u;
        const float s = S_s[f];
        float2 v;
        v.x = bg + s * ev_s[p];
        v.y = bg + s * ev_s[p + 1];
        mu2[q] = v;
    }

    // ---- deriv: 6*1280 = 7680 floats = 3840 float2 per block ----
    float2* dv2 = (float2*)(out_deriv + (size_t)b * (NF * M2 * 5));
    #pragma unroll
    for (int j = 0; j < 15; ++j) {
        const unsigned q = j * 256 + t;      // float2 index in [0,3840)
        const unsigned f = q / 640u;         // 640 float2 per field
        const unsigned e = (q * 2u) % 1280u; // float index within field chunk
        const unsigned p = e / 5u;
        const unsigned c = e - p * 5u;
        unsigned c1 = c + 1u;
        unsigned p1 = p;
        if (c1 == 5u) { c1 = 0u; p1 = p + 1u; }

        float v0 = A_s[f][c]  * ev_s[p]  + Bc_s[f][c]  * pd_s[e]     + (c  == 4u ? 1.f : 0.f);
        float v1 = A_s[f][c1] * ev_s[p1] + Bc_s[f][c1] * pd_s[e + 1] + (c1 == 4u ? 1.f : 0.f);
        float2 v; v.x = v0; v.y = v1;
        dv2[q] = v;
    }
}

extern "C" void kernel_launch(void* const* d_in, const int* in_sizes, int n_in,
                              void* d_out, int out_size, void* d_ws, size_t ws_size,
                              hipStream_t stream) {
    const float* params    = (const float*)d_in[0];   // (B,5)
    const float* mod       = (const float*)d_in[1];   // (B,6,6)
    const float* roipos    = (const float*)d_in[2];   // (B,2)
    const float* psf_ev    = (const float*)d_in[3];   // (B,256)
    const float* psf_deriv = (const float*)d_in[4];   // (B,256,5)

    const int B = in_sizes[0] / 5;                    // 16384
    const size_t mu_elems = (size_t)B * NF * M2;      // 25,165,824

    float* out_mu    = (float*)d_out;
    float* out_deriv = (float*)d_out + mu_elems;

    simflux_kernel<<<B, 256, 0, stream>>>(params, mod, roipos, psf_ev, psf_deriv,
                                          out_mu, out_deriv);
}